// Round 1
// baseline (245.902 us; speedup 1.0000x reference)
//
#include <hip/hip_runtime.h>
#include <hip/hip_bf16.h>

// out = kipf - lbda[:,None] * input
// N_NODES=100000, N_FEATURES=256, f32. Pure elementwise, HBM-bound.
// One thread per float4: 64 float4 per row -> row = idx >> 6.

__global__ __launch_bounds__(256) void damping_kernel(
    const float4* __restrict__ input4,
    const float4* __restrict__ kipf4,
    const float* __restrict__ lbda,
    float4* __restrict__ out4,
    int n4)  // total float4 elements = N_NODES * 64
{
    int i = blockIdx.x * blockDim.x + threadIdx.x;
    if (i >= n4) return;
    int row = i >> 6;               // 256 floats = 64 float4 per row
    float l = lbda[row];            // broadcast within row, cache-served
    float4 a = input4[i];
    float4 k = kipf4[i];
    float4 o;
    o.x = k.x - l * a.x;
    o.y = k.y - l * a.y;
    o.z = k.z - l * a.z;
    o.w = k.w - l * a.w;
    out4[i] = o;
}

extern "C" void kernel_launch(void* const* d_in, const int* in_sizes, int n_in,
                              void* d_out, int out_size, void* d_ws, size_t ws_size,
                              hipStream_t stream) {
    const float4* input4 = (const float4*)d_in[0];   // input_term (100000,256) f32
    const float4* kipf4  = (const float4*)d_in[1];   // kipf_term  (100000,256) f32
    const float*  lbda   = (const float*)d_in[2];    // lbda (100000,) f32
    // d_in[3] = spar (scalar int, always 1 in this path) -- unused
    float4* out4 = (float4*)d_out;

    int n4 = out_size / 4;                           // 100000*256/4 = 6,400,000
    int block = 256;
    int grid = (n4 + block - 1) / block;             // 25000 blocks
    damping_kernel<<<grid, block, 0, stream>>>(input4, kipf4, lbda, out4, n4);
}